// Round 4
// baseline (305.860 us; speedup 1.0000x reference)
//
#include <hip/hip_runtime.h>
#include <hip/hip_bf16.h>

typedef __bf16 bf16_t;
typedef __attribute__((ext_vector_type(8))) __bf16 bf16x8;
typedef __attribute__((ext_vector_type(4))) __bf16 bf16x4;
typedef __attribute__((ext_vector_type(4))) float f32x4;
typedef __attribute__((ext_vector_type(2))) float f32x2;

#define N1 16384
#define N2 4096
#define C1 128
#define C2 256
#define CIN 384
#define HD1 256
#define HD2 128
#define BDIM 4
#define CHUNK 512
#define NCHUNK 8   // N2 / CHUNK
#define NCAND 24   // NCHUNK * 3

// exact IEEE packed fp32 (v_pk_*): no fp-contract risk, 2 cands per inst
__device__ __forceinline__ f32x2 pk_add(f32x2 a, f32x2 b) {
  f32x2 r;
  asm("v_pk_add_f32 %0, %1, %2" : "=v"(r) : "v"(a), "v"(b));
  return r;
}
__device__ __forceinline__ f32x2 pk_mul(f32x2 a, f32x2 b) {
  f32x2 r;
  asm("v_pk_mul_f32 %0, %1, %2" : "=v"(r) : "v"(a), "v"(b));
  return r;
}

// predicated stable top-3 insert: strict < keeps earlier index on ties
__device__ __forceinline__ void ins3(float d, int j,
                                     float& d0, float& d1, float& d2,
                                     int& j0, int& j1, int& j2) {
  bool lt0 = d < d0, lt1 = d < d1, lt2 = d < d2;
  j2 = lt1 ? j1 : (lt2 ? j : j2);
  j1 = lt0 ? j0 : (lt1 ? j : j1);
  j0 = lt0 ? j : j0;
  d2 = __builtin_amdgcn_fmed3f(d, d1, d2);  // unconditional: med3 == new 3rd-best
  d1 = __builtin_amdgcn_fmed3f(d, d0, d1);
  d0 = fminf(d, d0);
}

// ---- prep: transpose + cast weights to bf16 ([K][N] fp32 -> [N][K] bf16) ----
__global__ void prep_w(const float* __restrict__ W1, const float* __restrict__ W2,
                       bf16_t* __restrict__ W1t, bf16_t* __restrict__ W2t) {
  int tid = blockIdx.x * 256 + threadIdx.x;
  if (tid < CIN * HD1) {
    int k = tid / HD1, n = tid % HD1;
    W1t[n * CIN + k] = (bf16_t)W1[tid];
  }
  if (tid < HD1 * HD2) {
    int k = tid / HD2, n = tid % HD2;
    W2t[n * HD1 + k] = (bf16_t)W2[tid];
  }
}

// ---- per-chunk top-3: block = 256 queries x one 512-point chunk ----
__global__ __launch_bounds__(256) void knn_chunk(
    const float* __restrict__ xyz1, const float* __restrict__ xyz2,
    float* __restrict__ candd, int* __restrict__ candj) {
  // NOTE: stores NEGATED coords so dist uses pk_add (a-b == a+(-b) exactly)
  __shared__ __align__(16) float sx[CHUNK], sy[CHUNK], sz[CHUNK];
  int b  = blockIdx.y;
  int ck = blockIdx.z;
  int i0 = blockIdx.x * 256;
  const float* x2b = xyz2 + ((size_t)b * N2 + (size_t)ck * CHUNK) * 3;
  for (int t = threadIdx.x; t < CHUNK * 3; t += 256) {
    float v = -x2b[t];
    int pt = t / 3, cd = t - pt * 3;
    if (cd == 0) sx[pt] = v;
    else if (cd == 1) sy[pt] = v;
    else sz[pt] = v;
  }
  __syncthreads();

  int i = i0 + threadIdx.x;
  const float* p = xyz1 + ((size_t)b * N1 + i) * 3;
  float px = p[0], py = p[1], pz = p[2];
  f32x2 px2 = {px, px}, py2 = {py, py}, pz2 = {pz, pz};

  float d0 = 3.4e38f, d1 = 3.4e38f, d2 = 3.4e38f;
  int   j0 = 0, j1 = 0, j2 = 0;
  for (int j = 0; j < CHUNK; j += 8) {
    // 6 ds_read_b128 per 8 candidates; explicit vars keep them in VGPRs
    float4 xa = *(const float4*)(sx + j), xb = *(const float4*)(sx + j + 4);
    float4 ya = *(const float4*)(sy + j), yb = *(const float4*)(sy + j + 4);
    float4 za = *(const float4*)(sz + j), zb = *(const float4*)(sz + j + 4);
#pragma unroll
    for (int h = 0; h < 4; ++h) {
      f32x2 nx, ny, nz;
      if (h == 0)      { nx = f32x2{xa.x, xa.y}; ny = f32x2{ya.x, ya.y}; nz = f32x2{za.x, za.y}; }
      else if (h == 1) { nx = f32x2{xa.z, xa.w}; ny = f32x2{ya.z, ya.w}; nz = f32x2{za.z, za.w}; }
      else if (h == 2) { nx = f32x2{xb.x, xb.y}; ny = f32x2{yb.x, yb.y}; nz = f32x2{zb.x, zb.y}; }
      else             { nx = f32x2{xb.z, xb.w}; ny = f32x2{yb.z, yb.w}; nz = f32x2{zb.z, zb.w}; }
      // exact reference arithmetic: (dx*dx + dy*dy) + dz*dz, round-to-nearest
      f32x2 dx = pk_add(px2, nx);
      f32x2 dy = pk_add(py2, ny);
      f32x2 dz = pk_add(pz2, nz);
      f32x2 sxx = pk_mul(dx, dx);
      f32x2 syy = pk_mul(dy, dy);
      f32x2 szz = pk_mul(dz, dz);
      f32x2 sxy = pk_add(sxx, syy);
      f32x2 dd  = pk_add(sxy, szz);
      int jj = j + h * 2;
      ins3(dd.x, jj,     d0, d1, d2, j0, j1, j2);
      ins3(dd.y, jj + 1, d0, d1, d2, j0, j1, j2);
    }
  }
  size_t qb = ((size_t)b * N1 + i) * NCAND + (size_t)ck * 3;
  int jbase = ck * CHUNK;
  candd[qb + 0] = d0; candd[qb + 1] = d1; candd[qb + 2] = d2;
  candj[qb + 0] = j0 + jbase; candj[qb + 1] = j1 + jbase; candj[qb + 2] = j2 + jbase;
}

// ---- merge 8x3 candidates -> final top-3 + normalized weights ----
__global__ __launch_bounds__(256) void knn_merge(
    const float* __restrict__ candd, const int* __restrict__ candj,
    float* __restrict__ wq, int* __restrict__ iq) {
  int q = blockIdx.x * 256 + threadIdx.x;
  const float* cd = candd + (size_t)q * NCAND;
  const int*   cj = candj + (size_t)q * NCAND;
  float d0 = 3.4e38f, d1 = 3.4e38f, d2 = 3.4e38f;
  int   j0 = 0, j1 = 0, j2 = 0;
  // chunk-major, within-chunk sorted ascending: strict < keeps earliest j on ties
#pragma unroll
  for (int c = 0; c < NCAND; ++c) {
    float d = cd[c]; int j = cj[c];
    ins3(d, j, d0, d1, d2, j0, j1, j2);
  }
  d0 = fmaxf(d0, 1e-10f); d1 = fmaxf(d1, 1e-10f); d2 = fmaxf(d2, 1e-10f);
  float w0 = 1.0f / d0, w1 = 1.0f / d1, w2 = 1.0f / d2;
  float ws = w0 + w1 + w2;
  wq[q * 3 + 0] = w0 / ws; wq[q * 3 + 1] = w1 / ws; wq[q * 3 + 2] = w2 / ws;
  iq[q * 3 + 0] = j0; iq[q * 3 + 1] = j1; iq[q * 3 + 2] = j2;
}

// ---- interp + concat -> NF bf16 [B*N1, 384]; one wave per point ----
__global__ __launch_bounds__(256) void interp_concat(
    const float* __restrict__ f1, const float* __restrict__ f2,
    const float* __restrict__ wq, const int* __restrict__ iq,
    bf16_t* __restrict__ NF) {
  int wv = threadIdx.x >> 6, ln = threadIdx.x & 63;
  size_t q = (size_t)blockIdx.x * 4 + wv;
  int b = (int)(q >> 14);  // N1 = 2^14
  float u0 = wq[q * 3 + 0], u1 = wq[q * 3 + 1], u2 = wq[q * 3 + 2];
  const float* f2b = f2 + (size_t)b * N2 * C2;
  const float* r0 = f2b + (size_t)iq[q * 3 + 0] * C2;
  const float* r1 = f2b + (size_t)iq[q * 3 + 1] * C2;
  const float* r2 = f2b + (size_t)iq[q * 3 + 2] * C2;
  int c = ln * 4;
  float4 v0 = *(const float4*)(r0 + c);
  float4 v1 = *(const float4*)(r1 + c);
  float4 v2 = *(const float4*)(r2 + c);
  bf16x4 o;
  o[0] = (bf16_t)(u0 * v0.x + u1 * v1.x + u2 * v2.x);
  o[1] = (bf16_t)(u0 * v0.y + u1 * v1.y + u2 * v2.y);
  o[2] = (bf16_t)(u0 * v0.z + u1 * v1.z + u2 * v2.z);
  o[3] = (bf16_t)(u0 * v0.w + u1 * v1.w + u2 * v2.w);
  *(bf16x4*)(NF + q * CIN + c) = o;
  if (ln < 32) {
    float4 g = *(const float4*)(f1 + q * C1 + c);
    bf16x4 og;
    og[0] = (bf16_t)g.x; og[1] = (bf16_t)g.y; og[2] = (bf16_t)g.z; og[3] = (bf16_t)g.w;
    *(bf16x4*)(NF + q * CIN + C2 + c) = og;
  }
}

// ---- bf16 MFMA GEMM, both operands K-contiguous (A [M][K], Bt [N][K]) ----
// C = relu(A @ Bt^T + bias); 128x128 tile, BK=32, 4 waves of 64x64
template <bool OUT_BF16>
__global__ __launch_bounds__(256) void gemm_bt(
    const bf16_t* __restrict__ A, const bf16_t* __restrict__ Bt,
    const float* __restrict__ bias, void* __restrict__ Cout,
    int M, int N, int K) {
  __shared__ __align__(16) bf16_t As[128 * 32];
  __shared__ __align__(16) bf16_t Bs[128 * 32];
  int tid  = threadIdx.x;
  int wv   = tid >> 6, ln = tid & 63;
  int quad = ln >> 4, lm = ln & 15;
  long row0 = (long)blockIdx.x * 128;
  int  col0 = blockIdx.y * 128;
  const bf16_t* Ab = A + row0 * K;
  const bf16_t* Bb = Bt + (long)col0 * K;
  f32x4 acc[4][4] = {};
  int wm = (wv >> 1) * 64, wn = (wv & 1) * 64;

  for (int k0 = 0; k0 < K; k0 += 32) {
#pragma unroll
    for (int t = 0; t < 2; ++t) {
      int c = t * 256 + tid;
      int r = c >> 2, kc = (c & 3) << 3;
      __builtin_amdgcn_global_load_lds(
          (const __attribute__((address_space(1))) void*)(Ab + (long)r * K + k0 + kc),
          (__attribute__((address_space(3))) void*)(As + (t * 256 + wv * 64) * 8),
          16, 0, 0);
      __builtin_amdgcn_global_load_lds(
          (const __attribute__((address_space(1))) void*)(Bb + (long)r * K + k0 + kc),
          (__attribute__((address_space(3))) void*)(Bs + (t * 256 + wv * 64) * 8),
          16, 0, 0);
    }
    __syncthreads();
    bf16x8 af[4], bfr[4];
#pragma unroll
    for (int mi = 0; mi < 4; ++mi)
      af[mi] = *(const bf16x8*)(As + (wm + mi * 16 + lm) * 32 + quad * 8);
#pragma unroll
    for (int ni = 0; ni < 4; ++ni)
      bfr[ni] = *(const bf16x8*)(Bs + (wn + ni * 16 + lm) * 32 + quad * 8);
#pragma unroll
    for (int mi = 0; mi < 4; ++mi)
#pragma unroll
      for (int ni = 0; ni < 4; ++ni)
        acc[mi][ni] = __builtin_amdgcn_mfma_f32_16x16x32_bf16(af[mi], bfr[ni],
                                                              acc[mi][ni], 0, 0, 0);
    __syncthreads();
  }

#pragma unroll
  for (int mi = 0; mi < 4; ++mi)
#pragma unroll
    for (int ni = 0; ni < 4; ++ni) {
      int col = col0 + wn + ni * 16 + lm;
      float bv = bias[col];
#pragma unroll
      for (int r = 0; r < 4; ++r) {
        long rowg = row0 + wm + mi * 16 + quad * 4 + r;
        float v = acc[mi][ni][r] + bv;
        v = fmaxf(v, 0.0f);
        if (OUT_BF16) ((bf16_t*)Cout)[rowg * N + col] = (bf16_t)v;
        else          ((float*)Cout)[rowg * N + col]  = v;
      }
    }
}

extern "C" void kernel_launch(void* const* d_in, const int* in_sizes, int n_in,
                              void* d_out, int out_size, void* d_ws, size_t ws_size,
                              hipStream_t stream) {
  const float* xyz1 = (const float*)d_in[0];
  const float* xyz2 = (const float*)d_in[1];
  const float* f1   = (const float*)d_in[2];
  const float* f2   = (const float*)d_in[3];
  const float* W1   = (const float*)d_in[4];
  const float* b1   = (const float*)d_in[5];
  const float* W2   = (const float*)d_in[6];
  const float* b2   = (const float*)d_in[7];
  float* out = (float*)d_out;

  const size_t NQ = (size_t)BDIM * N1;  // 65536
  char* ws = (char*)d_ws;
  bf16_t* W1t = (bf16_t*)ws;                         // 192 KB
  bf16_t* W2t = (bf16_t*)(ws + (256 << 10));         // 64 KB
  float*  wq  = (float*)(ws + (512 << 10));          // 786 KB
  int*    iq  = (int*)(ws + (1536 << 10));           // 786 KB
  bf16_t* NF  = (bf16_t*)(ws + (2560 << 10));        // 50.3 MB
  char*   hb  = ws + (2560 << 10) + NQ * CIN * 2;    // 33.6 MB region
  bf16_t* Hbuf  = (bf16_t*)hb;
  // candidates alias Hbuf (consumed by merge before gemm1 writes Hbuf)
  float*  candd = (float*)hb;                        // 6.3 MB
  int*    candj = (int*)(hb + NQ * NCAND * 4);       // 6.3 MB

  prep_w<<<dim3(384), dim3(256), 0, stream>>>(W1, W2, W1t, W2t);
  knn_chunk<<<dim3(N1 / 256, BDIM, NCHUNK), dim3(256), 0, stream>>>(
      xyz1, xyz2, candd, candj);
  knn_merge<<<dim3(NQ / 256), dim3(256), 0, stream>>>(candd, candj, wq, iq);
  interp_concat<<<dim3(NQ / 4), dim3(256), 0, stream>>>(f1, f2, wq, iq, NF);
  gemm_bt<true><<<dim3(NQ / 128, HD1 / 128), dim3(256), 0, stream>>>(
      NF, W1t, b1, (void*)Hbuf, NQ, HD1, CIN);
  gemm_bt<false><<<dim3(NQ / 128, HD2 / 128), dim3(256), 0, stream>>>(
      Hbuf, W2t, b2, (void*)out, NQ, HD2, HD1);
}

// Round 5
// 303.138 us; speedup vs baseline: 1.0090x; 1.0090x over previous
//
#include <hip/hip_runtime.h>
#include <hip/hip_bf16.h>

typedef __bf16 bf16_t;
typedef __attribute__((ext_vector_type(8))) __bf16 bf16x8;
typedef __attribute__((ext_vector_type(4))) __bf16 bf16x4;
typedef __attribute__((ext_vector_type(4))) float f32x4;

#define N1 16384
#define N2 4096
#define C1 128
#define C2 256
#define CIN 384
#define HD1 256
#define HD2 128
#define BDIM 4
#define CHUNK 512
#define NCHUNK 8   // N2 / CHUNK
#define NCAND 24   // NCHUNK * 3

// predicated stable top-3 insert: strict < keeps earlier index on ties
__device__ __forceinline__ void ins3(float d, int j,
                                     float& d0, float& d1, float& d2,
                                     int& j0, int& j1, int& j2) {
  bool lt0 = d < d0, lt1 = d < d1, lt2 = d < d2;
  j2 = lt1 ? j1 : (lt2 ? j : j2);
  j1 = lt0 ? j0 : (lt1 ? j : j1);
  j0 = lt0 ? j : j0;
  d2 = __builtin_amdgcn_fmed3f(d, d1, d2);  // == new 3rd-best unconditionally
  d1 = __builtin_amdgcn_fmed3f(d, d0, d1);
  d0 = fminf(d, d0);
}

// ---- prep: transpose + cast weights to bf16 ([K][N] fp32 -> [N][K] bf16) ----
__global__ void prep_w(const float* __restrict__ W1, const float* __restrict__ W2,
                       bf16_t* __restrict__ W1t, bf16_t* __restrict__ W2t) {
  int tid = blockIdx.x * 256 + threadIdx.x;
  if (tid < CIN * HD1) {
    int k = tid / HD1, n = tid % HD1;
    W1t[n * CIN + k] = (bf16_t)W1[tid];
  }
  if (tid < HD1 * HD2) {
    int k = tid / HD2, n = tid % HD2;
    W2t[n * HD1 + k] = (bf16_t)W2[tid];
  }
}

// ---- per-chunk top-3: block = 256 queries x one 512-point chunk ----
// __launch_bounds__(256,4): cap occupancy request at 4 waves/EU so the
// register allocator keeps the staged float4 batches in VGPRs (<=128 budget).
// Without it the compiler targets 8 waves/EU -> 20 VGPRs -> LDS re-reads.
__global__ __launch_bounds__(256, 4) void knn_chunk(
    const float* __restrict__ xyz1, const float* __restrict__ xyz2,
    float* __restrict__ candd, int* __restrict__ candj) {
  __shared__ __align__(16) float sx[CHUNK], sy[CHUNK], sz[CHUNK];
  int b  = blockIdx.y;
  int ck = blockIdx.z;
  int i0 = blockIdx.x * 256;
  const float* x2b = xyz2 + ((size_t)b * N2 + (size_t)ck * CHUNK) * 3;
  for (int t = threadIdx.x; t < CHUNK * 3; t += 256) {
    float v = x2b[t];
    int pt = t / 3, cd = t - pt * 3;
    if (cd == 0) sx[pt] = v;
    else if (cd == 1) sy[pt] = v;
    else sz[pt] = v;
  }
  __syncthreads();

  int i = i0 + threadIdx.x;
  const float* p = xyz1 + ((size_t)b * N1 + i) * 3;
  float px = p[0], py = p[1], pz = p[2];

  float d0 = 3.4e38f, d1 = 3.4e38f, d2 = 3.4e38f;
  int   j0 = 0, j1 = 0, j2 = 0;
  for (int j = 0; j < CHUNK; j += 8) {
    // 6 ds_read_b128 per 8 candidates; stays in VGPRs given the reg budget
    float4 xa = *(const float4*)(sx + j), xb = *(const float4*)(sx + j + 4);
    float4 ya = *(const float4*)(sy + j), yb = *(const float4*)(sy + j + 4);
    float4 za = *(const float4*)(sz + j), zb = *(const float4*)(sz + j + 4);
    float xs[8] = {xa.x, xa.y, xa.z, xa.w, xb.x, xb.y, xb.z, xb.w};
    float ys[8] = {ya.x, ya.y, ya.z, ya.w, yb.x, yb.y, yb.z, yb.w};
    float zs[8] = {za.x, za.y, za.z, za.w, zb.x, zb.y, zb.z, zb.w};
#pragma unroll
    for (int u = 0; u < 8; ++u) {
      // exact reference fp32 arithmetic (no FMA contraction) so selection matches
      float dx = __fsub_rn(px, xs[u]);
      float dy = __fsub_rn(py, ys[u]);
      float dz = __fsub_rn(pz, zs[u]);
      float d = __fadd_rn(__fadd_rn(__fmul_rn(dx, dx), __fmul_rn(dy, dy)),
                          __fmul_rn(dz, dz));
      ins3(d, j + u, d0, d1, d2, j0, j1, j2);
    }
  }
  size_t qb = ((size_t)b * N1 + i) * NCAND + (size_t)ck * 3;
  int jbase = ck * CHUNK;
  candd[qb + 0] = d0; candd[qb + 1] = d1; candd[qb + 2] = d2;
  candj[qb + 0] = j0 + jbase; candj[qb + 1] = j1 + jbase; candj[qb + 2] = j2 + jbase;
}

// ---- merge 8x3 candidates -> final top-3 + normalized weights ----
__global__ __launch_bounds__(256) void knn_merge(
    const float* __restrict__ candd, const int* __restrict__ candj,
    float* __restrict__ wq, int* __restrict__ iq) {
  int q = blockIdx.x * 256 + threadIdx.x;
  const float* cd = candd + (size_t)q * NCAND;
  const int*   cj = candj + (size_t)q * NCAND;
  float d0 = 3.4e38f, d1 = 3.4e38f, d2 = 3.4e38f;
  int   j0 = 0, j1 = 0, j2 = 0;
  // chunk-major, within-chunk sorted ascending: strict < keeps earliest j on ties
#pragma unroll
  for (int c = 0; c < NCAND; ++c) {
    ins3(cd[c], cj[c], d0, d1, d2, j0, j1, j2);
  }
  d0 = fmaxf(d0, 1e-10f); d1 = fmaxf(d1, 1e-10f); d2 = fmaxf(d2, 1e-10f);
  float w0 = 1.0f / d0, w1 = 1.0f / d1, w2 = 1.0f / d2;
  float ws = w0 + w1 + w2;
  wq[q * 3 + 0] = w0 / ws; wq[q * 3 + 1] = w1 / ws; wq[q * 3 + 2] = w2 / ws;
  iq[q * 3 + 0] = j0; iq[q * 3 + 1] = j1; iq[q * 3 + 2] = j2;
}

// ---- interp + concat -> NF bf16 [B*N1, 384]; one wave per point ----
__global__ __launch_bounds__(256) void interp_concat(
    const float* __restrict__ f1, const float* __restrict__ f2,
    const float* __restrict__ wq, const int* __restrict__ iq,
    bf16_t* __restrict__ NF) {
  int wv = threadIdx.x >> 6, ln = threadIdx.x & 63;
  size_t q = (size_t)blockIdx.x * 4 + wv;
  int b = (int)(q >> 14);  // N1 = 2^14
  float u0 = wq[q * 3 + 0], u1 = wq[q * 3 + 1], u2 = wq[q * 3 + 2];
  const float* f2b = f2 + (size_t)b * N2 * C2;
  const float* r0 = f2b + (size_t)iq[q * 3 + 0] * C2;
  const float* r1 = f2b + (size_t)iq[q * 3 + 1] * C2;
  const float* r2 = f2b + (size_t)iq[q * 3 + 2] * C2;
  int c = ln * 4;
  float4 v0 = *(const float4*)(r0 + c);
  float4 v1 = *(const float4*)(r1 + c);
  float4 v2 = *(const float4*)(r2 + c);
  bf16x4 o;
  o[0] = (bf16_t)(u0 * v0.x + u1 * v1.x + u2 * v2.x);
  o[1] = (bf16_t)(u0 * v0.y + u1 * v1.y + u2 * v2.y);
  o[2] = (bf16_t)(u0 * v0.z + u1 * v1.z + u2 * v2.z);
  o[3] = (bf16_t)(u0 * v0.w + u1 * v1.w + u2 * v2.w);
  *(bf16x4*)(NF + q * CIN + c) = o;
  if (ln < 32) {
    float4 g = *(const float4*)(f1 + q * C1 + c);
    bf16x4 og;
    og[0] = (bf16_t)g.x; og[1] = (bf16_t)g.y; og[2] = (bf16_t)g.z; og[3] = (bf16_t)g.w;
    *(bf16x4*)(NF + q * CIN + C2 + c) = og;
  }
}

// ---- bf16 MFMA GEMM, both operands K-contiguous (A [M][K], Bt [N][K]) ----
// C = relu(A @ Bt^T + bias); 128x128 tile, BK=32, 4 waves of 64x64
template <bool OUT_BF16>
__global__ __launch_bounds__(256) void gemm_bt(
    const bf16_t* __restrict__ A, const bf16_t* __restrict__ Bt,
    const float* __restrict__ bias, void* __restrict__ Cout,
    int M, int N, int K) {
  __shared__ __align__(16) bf16_t As[128 * 32];
  __shared__ __align__(16) bf16_t Bs[128 * 32];
  int tid  = threadIdx.x;
  int wv   = tid >> 6, ln = tid & 63;
  int quad = ln >> 4, lm = ln & 15;
  long row0 = (long)blockIdx.x * 128;
  int  col0 = blockIdx.y * 128;
  const bf16_t* Ab = A + row0 * K;
  const bf16_t* Bb = Bt + (long)col0 * K;
  f32x4 acc[4][4] = {};
  int wm = (wv >> 1) * 64, wn = (wv & 1) * 64;

  for (int k0 = 0; k0 < K; k0 += 32) {
#pragma unroll
    for (int t = 0; t < 2; ++t) {
      int c = t * 256 + tid;
      int r = c >> 2, kc = (c & 3) << 3;
      __builtin_amdgcn_global_load_lds(
          (const __attribute__((address_space(1))) void*)(Ab + (long)r * K + k0 + kc),
          (__attribute__((address_space(3))) void*)(As + (t * 256 + wv * 64) * 8),
          16, 0, 0);
      __builtin_amdgcn_global_load_lds(
          (const __attribute__((address_space(1))) void*)(Bb + (long)r * K + k0 + kc),
          (__attribute__((address_space(3))) void*)(Bs + (t * 256 + wv * 64) * 8),
          16, 0, 0);
    }
    __syncthreads();
    bf16x8 af[4], bfr[4];
#pragma unroll
    for (int mi = 0; mi < 4; ++mi)
      af[mi] = *(const bf16x8*)(As + (wm + mi * 16 + lm) * 32 + quad * 8);
#pragma unroll
    for (int ni = 0; ni < 4; ++ni)
      bfr[ni] = *(const bf16x8*)(Bs + (wn + ni * 16 + lm) * 32 + quad * 8);
#pragma unroll
    for (int mi = 0; mi < 4; ++mi)
#pragma unroll
      for (int ni = 0; ni < 4; ++ni)
        acc[mi][ni] = __builtin_amdgcn_mfma_f32_16x16x32_bf16(af[mi], bfr[ni],
                                                              acc[mi][ni], 0, 0, 0);
    __syncthreads();
  }

#pragma unroll
  for (int mi = 0; mi < 4; ++mi)
#pragma unroll
    for (int ni = 0; ni < 4; ++ni) {
      int col = col0 + wn + ni * 16 + lm;
      float bv = bias[col];
#pragma unroll
      for (int r = 0; r < 4; ++r) {
        long rowg = row0 + wm + mi * 16 + quad * 4 + r;
        float v = acc[mi][ni][r] + bv;
        v = fmaxf(v, 0.0f);
        if (OUT_BF16) ((bf16_t*)Cout)[rowg * N + col] = (bf16_t)v;
        else          ((float*)Cout)[rowg * N + col]  = v;
      }
    }
}

extern "C" void kernel_launch(void* const* d_in, const int* in_sizes, int n_in,
                              void* d_out, int out_size, void* d_ws, size_t ws_size,
                              hipStream_t stream) {
  const float* xyz1 = (const float*)d_in[0];
  const float* xyz2 = (const float*)d_in[1];
  const float* f1   = (const float*)d_in[2];
  const float* f2   = (const float*)d_in[3];
  const float* W1   = (const float*)d_in[4];
  const float* b1   = (const float*)d_in[5];
  const float* W2   = (const float*)d_in[6];
  const float* b2   = (const float*)d_in[7];
  float* out = (float*)d_out;

  const size_t NQ = (size_t)BDIM * N1;  // 65536
  char* ws = (char*)d_ws;
  bf16_t* W1t = (bf16_t*)ws;                         // 192 KB
  bf16_t* W2t = (bf16_t*)(ws + (256 << 10));         // 64 KB
  float*  wq  = (float*)(ws + (512 << 10));          // 786 KB
  int*    iq  = (int*)(ws + (1536 << 10));           // 786 KB
  bf16_t* NF  = (bf16_t*)(ws + (2560 << 10));        // 50.3 MB
  char*   hb  = ws + (2560 << 10) + NQ * CIN * 2;    // 33.6 MB region
  bf16_t* Hbuf  = (bf16_t*)hb;
  // candidates alias Hbuf (consumed by merge before gemm1 writes Hbuf)
  float*  candd = (float*)hb;                        // 6.3 MB
  int*    candj = (int*)(hb + NQ * NCAND * 4);       // 6.3 MB

  prep_w<<<dim3(384), dim3(256), 0, stream>>>(W1, W2, W1t, W2t);
  knn_chunk<<<dim3(N1 / 256, BDIM, NCHUNK), dim3(256), 0, stream>>>(
      xyz1, xyz2, candd, candj);
  knn_merge<<<dim3(NQ / 256), dim3(256), 0, stream>>>(candd, candj, wq, iq);
  interp_concat<<<dim3(NQ / 4), dim3(256), 0, stream>>>(f1, f2, wq, iq, NF);
  gemm_bt<true><<<dim3(NQ / 128, HD1 / 128), dim3(256), 0, stream>>>(
      NF, W1t, b1, (void*)Hbuf, NQ, HD1, CIN);
  gemm_bt<false><<<dim3(NQ / 128, HD2 / 128), dim3(256), 0, stream>>>(
      Hbuf, W2t, b2, (void*)out, NQ, HD2, HD1);
}

// Round 6
// 268.378 us; speedup vs baseline: 1.1397x; 1.1295x over previous
//
#include <hip/hip_runtime.h>
#include <hip/hip_bf16.h>

typedef __bf16 bf16_t;
typedef __attribute__((ext_vector_type(8))) __bf16 bf16x8;
typedef __attribute__((ext_vector_type(4))) __bf16 bf16x4;
typedef __attribute__((ext_vector_type(4))) float f32x4;

#define N1 16384
#define N2 4096
#define C1 128
#define C2 256
#define CIN 384
#define HD1 256
#define HD2 128
#define BDIM 4
#define CHUNK 1024
#define NCHUNK 4   // N2 / CHUNK
#define NCAND 12   // NCHUNK * 3

// ---- prep: transpose + cast weights to bf16 ([K][N] fp32 -> [N][K] bf16) ----
__global__ void prep_w(const float* __restrict__ W1, const float* __restrict__ W2,
                       bf16_t* __restrict__ W1t, bf16_t* __restrict__ W2t) {
  int tid = blockIdx.x * 256 + threadIdx.x;
  if (tid < CIN * HD1) {
    int k = tid / HD1, n = tid % HD1;
    W1t[n * CIN + k] = (bf16_t)W1[tid];
  }
  if (tid < HD1 * HD2) {
    int k = tid / HD2, n = tid % HD2;
    W2t[n * HD1 + k] = (bf16_t)W2[tid];
  }
}

// ---- per-chunk top-3: 256 queries/block x one 1024-point chunk ----
// Candidate coords are read with WAVE-UNIFORM addresses from a const
// __restrict__ pointer -> compiler emits s_load into SGPRs (scalar cache).
// VALU consumes them as SGPR operands: zero LDS-pipe traffic (the R2-R5
// plateau was the per-CU LDS issue pipe at 3 ds_read_b32/candidate).
__global__ __launch_bounds__(256) void knn_chunk(
    const float* __restrict__ xyz1, const float* __restrict__ xyz2,
    float* __restrict__ candd, int* __restrict__ candj) {
  int b  = blockIdx.y;
  int ck = blockIdx.z;
  int i0 = blockIdx.x * 256;

  int i = i0 + threadIdx.x;
  const float* p = xyz1 + ((size_t)b * N1 + i) * 3;
  float px = p[0], py = p[1], pz = p[2];

  const float* x2b = xyz2 + ((size_t)b * N2 + (size_t)ck * CHUNK) * 3;

  float d0 = 3.4e38f, d1 = 3.4e38f, d2 = 3.4e38f;
  int   j0 = 0, j1 = 0, j2 = 0;

  for (int j = 0; j < CHUNK; j += 16) {
    // 16 points = 48 floats = 12 uniform float4 loads -> s_load_dwordx16 x3
    float c[48];
    const float4* q = (const float4*)(x2b + 3 * j);
#pragma unroll
    for (int t = 0; t < 12; ++t) {
      float4 v = q[t];
      c[4 * t + 0] = v.x; c[4 * t + 1] = v.y; c[4 * t + 2] = v.z; c[4 * t + 3] = v.w;
    }
#pragma unroll
    for (int u = 0; u < 16; ++u) {
      // (cx-px) instead of (px-cx): negation-exact, square identical ->
      // distance bits match the reference fp32 arithmetic exactly
      float dx = __fsub_rn(c[3 * u + 0], px);
      float dy = __fsub_rn(c[3 * u + 1], py);
      float dz = __fsub_rn(c[3 * u + 2], pz);
      float d = __fadd_rn(__fadd_rn(__fmul_rn(dx, dx), __fmul_rn(dy, dy)),
                          __fmul_rn(dz, dz));
      int jj = j + u;
      if (d < d2) {  // strict <: earlier index wins ties (matches top_k)
        bool lt0 = d < d0, lt1 = d < d1;
        j2 = lt1 ? j1 : jj;
        j1 = lt0 ? j0 : (lt1 ? jj : j1);
        j0 = lt0 ? jj : j0;
        d2 = __builtin_amdgcn_fmed3f(d, d1, d2);
        d1 = __builtin_amdgcn_fmed3f(d, d0, d1);
        d0 = fminf(d, d0);
      }
    }
  }
  size_t qb = ((size_t)b * N1 + i) * NCAND + (size_t)ck * 3;
  int jbase = ck * CHUNK;
  candd[qb + 0] = d0; candd[qb + 1] = d1; candd[qb + 2] = d2;
  candj[qb + 0] = j0 + jbase; candj[qb + 1] = j1 + jbase; candj[qb + 2] = j2 + jbase;
}

// ---- merge 4x3 candidates -> final top-3 + normalized weights ----
__global__ __launch_bounds__(256) void knn_merge(
    const float* __restrict__ candd, const int* __restrict__ candj,
    float* __restrict__ wq, int* __restrict__ iq) {
  int q = blockIdx.x * 256 + threadIdx.x;
  const float* cd = candd + (size_t)q * NCAND;
  const int*   cj = candj + (size_t)q * NCAND;
  float d0 = 3.4e38f, d1 = 3.4e38f, d2 = 3.4e38f;
  int   j0 = 0, j1 = 0, j2 = 0;
  // chunk-major, within-chunk sorted ascending: strict < keeps earliest j on ties
#pragma unroll
  for (int c = 0; c < NCAND; ++c) {
    float d = cd[c]; int j = cj[c];
    bool lt0 = d < d0, lt1 = d < d1, lt2 = d < d2;
    j2 = lt1 ? j1 : (lt2 ? j : j2);
    j1 = lt0 ? j0 : (lt1 ? j : j1);
    j0 = lt0 ? j : j0;
    d2 = __builtin_amdgcn_fmed3f(d, d1, d2);
    d1 = __builtin_amdgcn_fmed3f(d, d0, d1);
    d0 = fminf(d, d0);
  }
  d0 = fmaxf(d0, 1e-10f); d1 = fmaxf(d1, 1e-10f); d2 = fmaxf(d2, 1e-10f);
  float w0 = 1.0f / d0, w1 = 1.0f / d1, w2 = 1.0f / d2;
  float ws = w0 + w1 + w2;
  wq[q * 3 + 0] = w0 / ws; wq[q * 3 + 1] = w1 / ws; wq[q * 3 + 2] = w2 / ws;
  iq[q * 3 + 0] = j0; iq[q * 3 + 1] = j1; iq[q * 3 + 2] = j2;
}

// ---- interp + concat -> NF bf16 [B*N1, 384]; one wave per point ----
__global__ __launch_bounds__(256) void interp_concat(
    const float* __restrict__ f1, const float* __restrict__ f2,
    const float* __restrict__ wq, const int* __restrict__ iq,
    bf16_t* __restrict__ NF) {
  int wv = threadIdx.x >> 6, ln = threadIdx.x & 63;
  size_t q = (size_t)blockIdx.x * 4 + wv;
  int b = (int)(q >> 14);  // N1 = 2^14
  float u0 = wq[q * 3 + 0], u1 = wq[q * 3 + 1], u2 = wq[q * 3 + 2];
  const float* f2b = f2 + (size_t)b * N2 * C2;
  const float* r0 = f2b + (size_t)iq[q * 3 + 0] * C2;
  const float* r1 = f2b + (size_t)iq[q * 3 + 1] * C2;
  const float* r2 = f2b + (size_t)iq[q * 3 + 2] * C2;
  int c = ln * 4;
  float4 v0 = *(const float4*)(r0 + c);
  float4 v1 = *(const float4*)(r1 + c);
  float4 v2 = *(const float4*)(r2 + c);
  bf16x4 o;
  o[0] = (bf16_t)(u0 * v0.x + u1 * v1.x + u2 * v2.x);
  o[1] = (bf16_t)(u0 * v0.y + u1 * v1.y + u2 * v2.y);
  o[2] = (bf16_t)(u0 * v0.z + u1 * v1.z + u2 * v2.z);
  o[3] = (bf16_t)(u0 * v0.w + u1 * v1.w + u2 * v2.w);
  *(bf16x4*)(NF + q * CIN + c) = o;
  if (ln < 32) {
    float4 g = *(const float4*)(f1 + q * C1 + c);
    bf16x4 og;
    og[0] = (bf16_t)g.x; og[1] = (bf16_t)g.y; og[2] = (bf16_t)g.z; og[3] = (bf16_t)g.w;
    *(bf16x4*)(NF + q * CIN + C2 + c) = og;
  }
}

// ---- bf16 MFMA GEMM, both operands K-contiguous (A [M][K], Bt [N][K]) ----
// C = relu(A @ Bt^T + bias); 128x128 tile, BK=32, 4 waves of 64x64
template <bool OUT_BF16>
__global__ __launch_bounds__(256) void gemm_bt(
    const bf16_t* __restrict__ A, const bf16_t* __restrict__ Bt,
    const float* __restrict__ bias, void* __restrict__ Cout,
    int M, int N, int K) {
  __shared__ __align__(16) bf16_t As[128 * 32];
  __shared__ __align__(16) bf16_t Bs[128 * 32];
  int tid  = threadIdx.x;
  int wv   = tid >> 6, ln = tid & 63;
  int quad = ln >> 4, lm = ln & 15;
  long row0 = (long)blockIdx.x * 128;
  int  col0 = blockIdx.y * 128;
  const bf16_t* Ab = A + row0 * K;
  const bf16_t* Bb = Bt + (long)col0 * K;
  f32x4 acc[4][4] = {};
  int wm = (wv >> 1) * 64, wn = (wv & 1) * 64;

  for (int k0 = 0; k0 < K; k0 += 32) {
#pragma unroll
    for (int t = 0; t < 2; ++t) {
      int c = t * 256 + tid;
      int r = c >> 2, kc = (c & 3) << 3;
      __builtin_amdgcn_global_load_lds(
          (const __attribute__((address_space(1))) void*)(Ab + (long)r * K + k0 + kc),
          (__attribute__((address_space(3))) void*)(As + (t * 256 + wv * 64) * 8),
          16, 0, 0);
      __builtin_amdgcn_global_load_lds(
          (const __attribute__((address_space(1))) void*)(Bb + (long)r * K + k0 + kc),
          (__attribute__((address_space(3))) void*)(Bs + (t * 256 + wv * 64) * 8),
          16, 0, 0);
    }
    __syncthreads();
    bf16x8 af[4], bfr[4];
#pragma unroll
    for (int mi = 0; mi < 4; ++mi)
      af[mi] = *(const bf16x8*)(As + (wm + mi * 16 + lm) * 32 + quad * 8);
#pragma unroll
    for (int ni = 0; ni < 4; ++ni)
      bfr[ni] = *(const bf16x8*)(Bs + (wn + ni * 16 + lm) * 32 + quad * 8);
#pragma unroll
    for (int mi = 0; mi < 4; ++mi)
#pragma unroll
      for (int ni = 0; ni < 4; ++ni)
        acc[mi][ni] = __builtin_amdgcn_mfma_f32_16x16x32_bf16(af[mi], bfr[ni],
                                                              acc[mi][ni], 0, 0, 0);
    __syncthreads();
  }

#pragma unroll
  for (int mi = 0; mi < 4; ++mi)
#pragma unroll
    for (int ni = 0; ni < 4; ++ni) {
      int col = col0 + wn + ni * 16 + lm;
      float bv = bias[col];
#pragma unroll
      for (int r = 0; r < 4; ++r) {
        long rowg = row0 + wm + mi * 16 + quad * 4 + r;
        float v = acc[mi][ni][r] + bv;
        v = fmaxf(v, 0.0f);
        if (OUT_BF16) ((bf16_t*)Cout)[rowg * N + col] = (bf16_t)v;
        else          ((float*)Cout)[rowg * N + col]  = v;
      }
    }
}

extern "C" void kernel_launch(void* const* d_in, const int* in_sizes, int n_in,
                              void* d_out, int out_size, void* d_ws, size_t ws_size,
                              hipStream_t stream) {
  const float* xyz1 = (const float*)d_in[0];
  const float* xyz2 = (const float*)d_in[1];
  const float* f1   = (const float*)d_in[2];
  const float* f2   = (const float*)d_in[3];
  const float* W1   = (const float*)d_in[4];
  const float* b1   = (const float*)d_in[5];
  const float* W2   = (const float*)d_in[6];
  const float* b2   = (const float*)d_in[7];
  float* out = (float*)d_out;

  const size_t NQ = (size_t)BDIM * N1;  // 65536
  char* ws = (char*)d_ws;
  bf16_t* W1t = (bf16_t*)ws;                         // 192 KB
  bf16_t* W2t = (bf16_t*)(ws + (256 << 10));         // 64 KB
  float*  wq  = (float*)(ws + (512 << 10));          // 786 KB
  int*    iq  = (int*)(ws + (1536 << 10));           // 786 KB
  bf16_t* NF  = (bf16_t*)(ws + (2560 << 10));        // 50.3 MB
  char*   hb  = ws + (2560 << 10) + NQ * CIN * 2;    // 33.6 MB region
  bf16_t* Hbuf  = (bf16_t*)hb;
  // candidates alias Hbuf (consumed by merge before gemm1 writes Hbuf)
  float*  candd = (float*)hb;                        // 3.1 MB
  int*    candj = (int*)(hb + NQ * NCAND * 4);       // 3.1 MB

  prep_w<<<dim3(384), dim3(256), 0, stream>>>(W1, W2, W1t, W2t);
  knn_chunk<<<dim3(N1 / 256, BDIM, NCHUNK), dim3(256), 0, stream>>>(
      xyz1, xyz2, candd, candj);
  knn_merge<<<dim3(NQ / 256), dim3(256), 0, stream>>>(candd, candj, wq, iq);
  interp_concat<<<dim3(NQ / 4), dim3(256), 0, stream>>>(f1, f2, wq, iq, NF);
  gemm_bt<true><<<dim3(NQ / 128, HD1 / 128), dim3(256), 0, stream>>>(
      NF, W1t, b1, (void*)Hbuf, NQ, HD1, CIN);
  gemm_bt<false><<<dim3(NQ / 128, HD2 / 128), dim3(256), 0, stream>>>(
      Hbuf, W2t, b2, (void*)out, NQ, HD2, HD1);
}

// Round 9
// 265.508 us; speedup vs baseline: 1.1520x; 1.0108x over previous
//
#include <hip/hip_runtime.h>
#include <hip/hip_bf16.h>

typedef __bf16 bf16_t;
typedef __attribute__((ext_vector_type(8))) __bf16 bf16x8;
typedef __attribute__((ext_vector_type(4))) __bf16 bf16x4;
typedef __attribute__((ext_vector_type(4))) float f32x4;

#define N1 16384
#define N2 4096
#define C1 128
#define C2 256
#define CIN 384
#define HD1 256
#define HD2 128
#define BDIM 4
#define CHUNK 512
#define NCHUNK 8   // N2 / CHUNK
#define NCAND 24   // NCHUNK * 3

// ---- prep: transpose + cast weights to bf16 ([K][N] fp32 -> [N][K] bf16) ----
__global__ void prep_w(const float* __restrict__ W1, const float* __restrict__ W2,
                       bf16_t* __restrict__ W1t, bf16_t* __restrict__ W2t) {
  int tid = blockIdx.x * 256 + threadIdx.x;
  if (tid < CIN * HD1) {
    int k = tid / HD1, n = tid % HD1;
    W1t[n * CIN + k] = (bf16_t)W1[tid];
  }
  if (tid < HD1 * HD2) {
    int k = tid / HD2, n = tid % HD2;
    W2t[n * HD1 + k] = (bf16_t)W2[tid];
  }
}

// ---- per-chunk top-3: 256 queries/block x one 512-point chunk ----
// Identical scan body to the R6-validated kernel (coords via wave-uniform
// s_load into SGPRs: LDS=0, bank-conflicts=0, 21.8 inst/cand if-converted).
// Only delta: CHUNK 1024->512 (NCHUNK 8) -> 2048 blocks = 8 blocks/CU =
// 32 waves/CU, to hide s_load lgkmcnt waits (R6: VALUBusy 72%, Occ 36%).
// NO vote intrinsics / NO inline asm (R7/R8 container-failure suspects).
__global__ __launch_bounds__(256) void knn_chunk(
    const float* __restrict__ xyz1, const float* __restrict__ xyz2,
    float* __restrict__ candd, int* __restrict__ candj) {
  int b  = blockIdx.y;
  int ck = blockIdx.z;
  int i  = blockIdx.x * 256 + threadIdx.x;
  const float* p = xyz1 + ((size_t)b * N1 + i) * 3;
  float px = p[0], py = p[1], pz = p[2];

  const float* x2b = xyz2 + ((size_t)b * N2 + (size_t)ck * CHUNK) * 3;

  float d0 = 3.4e38f, d1 = 3.4e38f, d2 = 3.4e38f;
  int   j0 = 0, j1 = 0, j2 = 0;

  for (int j = 0; j < CHUNK; j += 16) {
    // 16 points = 48 floats, uniform addresses -> 3x s_load_dwordx16
    float c[48];
    const float4* q = (const float4*)(x2b + 3 * j);
#pragma unroll
    for (int t = 0; t < 12; ++t) {
      float4 v = q[t];
      c[4 * t + 0] = v.x; c[4 * t + 1] = v.y; c[4 * t + 2] = v.z; c[4 * t + 3] = v.w;
    }
#pragma unroll
    for (int u = 0; u < 16; ++u) {
      // (cx-px): negation-exact vs reference (px-cx); square identical ->
      // selection matches the fp32 reference bit-for-bit
      float dx = __fsub_rn(c[3 * u + 0], px);
      float dy = __fsub_rn(c[3 * u + 1], py);
      float dz = __fsub_rn(c[3 * u + 2], pz);
      float d = __fadd_rn(__fadd_rn(__fmul_rn(dx, dx), __fmul_rn(dy, dy)),
                          __fmul_rn(dz, dz));
      int jj = j + u;
      if (d < d2) {  // strict <: earlier index wins ties (matches top_k)
        bool lt0 = d < d0, lt1 = d < d1;
        j2 = lt1 ? j1 : jj;
        j1 = lt0 ? j0 : (lt1 ? jj : j1);
        j0 = lt0 ? jj : j0;
        d2 = __builtin_amdgcn_fmed3f(d, d1, d2);
        d1 = __builtin_amdgcn_fmed3f(d, d0, d1);
        d0 = fminf(d, d0);
      }
    }
  }
  size_t qb = ((size_t)b * N1 + i) * NCAND + (size_t)ck * 3;
  int jbase = ck * CHUNK;
  candd[qb + 0] = d0; candd[qb + 1] = d1; candd[qb + 2] = d2;
  candj[qb + 0] = j0 + jbase; candj[qb + 1] = j1 + jbase; candj[qb + 2] = j2 + jbase;
}

// ---- merge 8x3 candidates -> final top-3 + normalized weights ----
__global__ __launch_bounds__(256) void knn_merge(
    const float* __restrict__ candd, const int* __restrict__ candj,
    float* __restrict__ wq, int* __restrict__ iq) {
  int q = blockIdx.x * 256 + threadIdx.x;
  const float* cd = candd + (size_t)q * NCAND;
  const int*   cj = candj + (size_t)q * NCAND;
  float d0 = 3.4e38f, d1 = 3.4e38f, d2 = 3.4e38f;
  int   j0 = 0, j1 = 0, j2 = 0;
  // chunk-major, within-chunk sorted ascending: strict < keeps earliest j on ties
#pragma unroll
  for (int c = 0; c < NCAND; ++c) {
    float d = cd[c]; int j = cj[c];
    bool p0 = d < d0, p1 = d < d1, p2 = d < d2;
    j2 = p1 ? j1 : (p2 ? j : j2);
    j1 = p0 ? j0 : (p1 ? j : j1);
    j0 = p0 ? j : j0;
    d2 = __builtin_amdgcn_fmed3f(d, d1, d2);
    d1 = __builtin_amdgcn_fmed3f(d, d0, d1);
    d0 = fminf(d, d0);
  }
  d0 = fmaxf(d0, 1e-10f); d1 = fmaxf(d1, 1e-10f); d2 = fmaxf(d2, 1e-10f);
  float w0 = 1.0f / d0, w1 = 1.0f / d1, w2 = 1.0f / d2;
  float ws = w0 + w1 + w2;
  wq[q * 3 + 0] = w0 / ws; wq[q * 3 + 1] = w1 / ws; wq[q * 3 + 2] = w2 / ws;
  iq[q * 3 + 0] = j0; iq[q * 3 + 1] = j1; iq[q * 3 + 2] = j2;
}

// ---- interp + concat -> NF bf16 [B*N1, 384]; one wave per point ----
__global__ __launch_bounds__(256) void interp_concat(
    const float* __restrict__ f1, const float* __restrict__ f2,
    const float* __restrict__ wq, const int* __restrict__ iq,
    bf16_t* __restrict__ NF) {
  int wv = threadIdx.x >> 6, ln = threadIdx.x & 63;
  size_t q = (size_t)blockIdx.x * 4 + wv;
  int b = (int)(q >> 14);  // N1 = 2^14
  float u0 = wq[q * 3 + 0], u1 = wq[q * 3 + 1], u2 = wq[q * 3 + 2];
  const float* f2b = f2 + (size_t)b * N2 * C2;
  const float* r0 = f2b + (size_t)iq[q * 3 + 0] * C2;
  const float* r1 = f2b + (size_t)iq[q * 3 + 1] * C2;
  const float* r2 = f2b + (size_t)iq[q * 3 + 2] * C2;
  int c = ln * 4;
  float4 v0 = *(const float4*)(r0 + c);
  float4 v1 = *(const float4*)(r1 + c);
  float4 v2 = *(const float4*)(r2 + c);
  bf16x4 o;
  o[0] = (bf16_t)(u0 * v0.x + u1 * v1.x + u2 * v2.x);
  o[1] = (bf16_t)(u0 * v0.y + u1 * v1.y + u2 * v2.y);
  o[2] = (bf16_t)(u0 * v0.z + u1 * v1.z + u2 * v2.z);
  o[3] = (bf16_t)(u0 * v0.w + u1 * v1.w + u2 * v2.w);
  *(bf16x4*)(NF + q * CIN + c) = o;
  if (ln < 32) {
    float4 g = *(const float4*)(f1 + q * C1 + c);
    bf16x4 og;
    og[0] = (bf16_t)g.x; og[1] = (bf16_t)g.y; og[2] = (bf16_t)g.z; og[3] = (bf16_t)g.w;
    *(bf16x4*)(NF + q * CIN + C2 + c) = og;
  }
}

// ---- bf16 MFMA GEMM, both operands K-contiguous (A [M][K], Bt [N][K]) ----
// C = relu(A @ Bt^T + bias); 128x128 tile, BK=32, 4 waves of 64x64
template <bool OUT_BF16>
__global__ __launch_bounds__(256) void gemm_bt(
    const bf16_t* __restrict__ A, const bf16_t* __restrict__ Bt,
    const float* __restrict__ bias, void* __restrict__ Cout,
    int M, int N, int K) {
  __shared__ __align__(16) bf16_t As[128 * 32];
  __shared__ __align__(16) bf16_t Bs[128 * 32];
  int tid  = threadIdx.x;
  int wv   = tid >> 6, ln = tid & 63;
  int quad = ln >> 4, lm = ln & 15;
  long row0 = (long)blockIdx.x * 128;
  int  col0 = blockIdx.y * 128;
  const bf16_t* Ab = A + row0 * K;
  const bf16_t* Bb = Bt + (long)col0 * K;
  f32x4 acc[4][4] = {};
  int wm = (wv >> 1) * 64, wn = (wv & 1) * 64;

  for (int k0 = 0; k0 < K; k0 += 32) {
#pragma unroll
    for (int t = 0; t < 2; ++t) {
      int c = t * 256 + tid;
      int r = c >> 2, kc = (c & 3) << 3;
      __builtin_amdgcn_global_load_lds(
          (const __attribute__((address_space(1))) void*)(Ab + (long)r * K + k0 + kc),
          (__attribute__((address_space(3))) void*)(As + (t * 256 + wv * 64) * 8),
          16, 0, 0);
      __builtin_amdgcn_global_load_lds(
          (const __attribute__((address_space(1))) void*)(Bb + (long)r * K + k0 + kc),
          (__attribute__((address_space(3))) void*)(Bs + (t * 256 + wv * 64) * 8),
          16, 0, 0);
    }
    __syncthreads();
    bf16x8 af[4], bfr[4];
#pragma unroll
    for (int mi = 0; mi < 4; ++mi)
      af[mi] = *(const bf16x8*)(As + (wm + mi * 16 + lm) * 32 + quad * 8);
#pragma unroll
    for (int ni = 0; ni < 4; ++ni)
      bfr[ni] = *(const bf16x8*)(Bs + (wn + ni * 16 + lm) * 32 + quad * 8);
#pragma unroll
    for (int mi = 0; mi < 4; ++mi)
#pragma unroll
      for (int ni = 0; ni < 4; ++ni)
        acc[mi][ni] = __builtin_amdgcn_mfma_f32_16x16x32_bf16(af[mi], bfr[ni],
                                                              acc[mi][ni], 0, 0, 0);
    __syncthreads();
  }

#pragma unroll
  for (int mi = 0; mi < 4; ++mi)
#pragma unroll
    for (int ni = 0; ni < 4; ++ni) {
      int col = col0 + wn + ni * 16 + lm;
      float bv = bias[col];
#pragma unroll
      for (int r = 0; r < 4; ++r) {
        long rowg = row0 + wm + mi * 16 + quad * 4 + r;
        float v = acc[mi][ni][r] + bv;
        v = fmaxf(v, 0.0f);
        if (OUT_BF16) ((bf16_t*)Cout)[rowg * N + col] = (bf16_t)v;
        else          ((float*)Cout)[rowg * N + col]  = v;
      }
    }
}

extern "C" void kernel_launch(void* const* d_in, const int* in_sizes, int n_in,
                              void* d_out, int out_size, void* d_ws, size_t ws_size,
                              hipStream_t stream) {
  const float* xyz1 = (const float*)d_in[0];
  const float* xyz2 = (const float*)d_in[1];
  const float* f1   = (const float*)d_in[2];
  const float* f2   = (const float*)d_in[3];
  const float* W1   = (const float*)d_in[4];
  const float* b1   = (const float*)d_in[5];
  const float* W2   = (const float*)d_in[6];
  const float* b2   = (const float*)d_in[7];
  float* out = (float*)d_out;

  const size_t NQ = (size_t)BDIM * N1;  // 65536
  char* ws = (char*)d_ws;
  bf16_t* W1t = (bf16_t*)ws;                         // 192 KB
  bf16_t* W2t = (bf16_t*)(ws + (256 << 10));         // 64 KB
  float*  wq  = (float*)(ws + (512 << 10));          // 768 KB
  int*    iq  = (int*)(ws + (1536 << 10));           // 768 KB
  bf16_t* NF  = (bf16_t*)(ws + (2560 << 10));        // 48 MB
  char*   hb  = ws + (2560 << 10) + NQ * CIN * 2;    // 33.5 MB region
  bf16_t* Hbuf  = (bf16_t*)hb;
  // candidates alias Hbuf (consumed by merge before gemm1 writes Hbuf)
  float*  candd = (float*)hb;                        // 6.3 MB
  int*    candj = (int*)(hb + NQ * NCAND * 4);       // 6.3 MB

  prep_w<<<dim3(384), dim3(256), 0, stream>>>(W1, W2, W1t, W2t);
  knn_chunk<<<dim3(N1 / 256, BDIM, NCHUNK), dim3(256), 0, stream>>>(
      xyz1, xyz2, candd, candj);
  knn_merge<<<dim3(NQ / 256), dim3(256), 0, stream>>>(candd, candj, wq, iq);
  interp_concat<<<dim3(NQ / 4), dim3(256), 0, stream>>>(f1, f2, wq, iq, NF);
  gemm_bt<true><<<dim3(NQ / 128, HD1 / 128), dim3(256), 0, stream>>>(
      NF, W1t, b1, (void*)Hbuf, NQ, HD1, CIN);
  gemm_bt<false><<<dim3(NQ / 128, HD2 / 128), dim3(256), 0, stream>>>(
      Hbuf, W2t, b2, (void*)out, NQ, HD2, HD1);
}